// Round 13
// baseline (218.076 us; speedup 1.0000x reference)
//
#include <hip/hip_runtime.h>
#include <hip/hip_bf16.h>
#include <math.h>

#define BB 2
#define DIMC 256
#define FF 4
#define HH 16
#define WW 16
#define GRP 4
#define CPG 64        // DIM/GROUPS
#define ODIM 128      // OFF_DIMS
#define PQ 1024       // F*H*W
#define PJ 128        // FD*HD*WD
#define NBG 8         // B*GROUPS
#define INNERC 512

typedef short bf16x8 __attribute__((ext_vector_type(8)));
typedef float f32x4 __attribute__((ext_vector_type(4)));
typedef float f32x2 __attribute__((ext_vector_type(2)));

__device__ __forceinline__ unsigned int bfbits(float x) {
    union { float f; unsigned int u; } v; v.f = x;
    unsigned int u = v.u;
    unsigned int r = u + 0x7fffu + ((u >> 16) & 1u);
    return r >> 16;
}

__device__ __forceinline__ unsigned int pack_bf2(f32x2 a) {
    float2 ff = make_float2(a.x, a.y);
    __hip_bfloat162 h2 = __float22bfloat162_rn(ff);
    union { __hip_bfloat162 h; unsigned int u; } c; c.h = h2;
    return c.u;
}

// ---- fused: q = grouped 1x1 conv (LDS-resident) -> depthwise conv + GELU
__global__ __launch_bounds__(512) void k_qdw(
    const float* __restrict__ x, const float* __restrict__ wq,
    const float* __restrict__ dww, const float* __restrict__ dwb,
    float* __restrict__ q, float* __restrict__ act) {
    __shared__ float qs[1024 * 4];   // qs[p][k] : 16 KB
    int og = blockIdx.x & 31, bg = blockIdx.x >> 5;
    int b = bg >> 2, g = bg & 3;
    int o0 = og * 4;
    int tid = threadIdx.x;           // 0..511
    const float* xp = x + (size_t)(b * DIMC + g * CPG) * PQ;
    const float* wp = wq + (size_t)(g * ODIM + o0) * CPG;

    float accq[2][4] = {};
    #pragma unroll 8
    for (int i = 0; i < CPG; ++i) {
        float wv[4];
        #pragma unroll
        for (int k = 0; k < 4; ++k) wv[k] = wp[k * CPG + i];
        #pragma unroll
        for (int pi = 0; pi < 2; ++pi) {
            float xv = xp[(size_t)i * PQ + tid + pi * 512];
            #pragma unroll
            for (int k = 0; k < 4; ++k) accq[pi][k] += xv * wv[k];
        }
    }
    #pragma unroll
    for (int pi = 0; pi < 2; ++pi) {
        int p = tid + pi * 512;
        *(float4*)&qs[p * 4] = make_float4(accq[pi][0], accq[pi][1], accq[pi][2], accq[pi][3]);
        #pragma unroll
        for (int k = 0; k < 4; ++k)
            q[(size_t)(bg * ODIM + o0 + k) * PQ + p] = accq[pi][k];
    }
    __syncthreads();

    {
        int cl = tid & 3, j = tid >> 2;   // 512 units = 128 j x 4 c
        int c = o0 + cl;
        int xo = j & 7, yo = (j >> 3) & 7, zo = j >> 6;
        const float* wd = dww + c * 64;
        float acc = dwb[c];
        #pragma unroll
        for (int kz = 0; kz < 4; ++kz) {
            int z = 2 * zo - 1 + kz;
            if (z < 0 || z >= FF) continue;
            #pragma unroll
            for (int ky = 0; ky < 4; ++ky) {
                int y = 2 * yo - 1 + ky;
                if (y < 0 || y >= HH) continue;
                #pragma unroll
                for (int kx = 0; kx < 4; ++kx) {
                    int xx = 2 * xo - 1 + kx;
                    if (xx < 0 || xx >= WW) continue;
                    acc += qs[((z * HH + y) * WW + xx) * 4 + cl] * wd[(kz * 4 + ky) * 4 + kx];
                }
            }
        }
        act[((size_t)bg * PJ + j) * ODIM + c] =
            0.5f * acc * (1.0f + erff(acc * 0.70710678118654752f));
    }
}

// ------- fused offsets -> grid -> trilinear sample -> k/v proj; 2 j's per block
__global__ __launch_bounds__(256) void k_kvf(
    const float* __restrict__ act, const float* __restrict__ pw,
    const float* __restrict__ x, const float* __restrict__ wk,
    const float* __restrict__ wv, float* __restrict__ gkv,
    float* __restrict__ kk2, float* __restrict__ vvT2) {
    __shared__ float red2[2][6];
    __shared__ float crd[2][3];
    __shared__ float kvs[2][64];
    int blk = blockIdx.x;            // bg*64 + jt
    int jt = blk & 63, bg = blk >> 6;
    int b = bg >> 2, g = bg & 3;
    int tid = threadIdx.x;
    int half = tid >> 7;
    int t = tid & 127;
    int j = jt * 2 + half;
    int wv_ = t >> 6;

    float val = act[((size_t)bg * PJ + j) * ODIM + t];
    float s0 = val * pw[t];
    float s1 = val * pw[ODIM + t];
    float s2 = val * pw[2 * ODIM + t];
    #pragma unroll
    for (int off = 32; off; off >>= 1) {
        s0 += __shfl_xor(s0, off);
        s1 += __shfl_xor(s1, off);
        s2 += __shfl_xor(s2, off);
    }
    if ((t & 63) == 0) {
        red2[half][wv_ * 3] = s0; red2[half][wv_ * 3 + 1] = s1; red2[half][wv_ * 3 + 2] = s2;
    }
    __syncthreads();
    if (t == 0) {
        s0 = red2[half][0] + red2[half][3];
        s1 = red2[half][1] + red2[half][4];
        s2 = red2[half][2] + red2[half][5];
        float xo = (float)(j & 7), yo = (float)((j >> 3) & 7), zo = (float)(j >> 6);
        float vf = zo + 2.f * tanhf(s0);
        float vh = yo + 2.f * tanhf(s1);
        float vw = xo + 2.f * tanhf(s2);
        float c0 = 2.f * vf - 1.f;
        float c1 = 2.f * vh / 7.f - 1.f;
        float c2 = 2.f * vw / 7.f - 1.f;
        crd[half][0] = c0; crd[half][1] = c1; crd[half][2] = c2;
        gkv[(bg * PJ + j) * 3 + 0] = c0;
        gkv[(bg * PJ + j) * 3 + 1] = c1;
        gkv[(bg * PJ + j) * 3 + 2] = c2;
    }
    __syncthreads();

    // BUG-COMPATIBLE: crd[0] (f-coord) -> x/W axis, crd[1] -> y/H, crd[2] (w) -> z/D.
    if (t < 64) {
        float ix = ((crd[half][0] + 1.f) * WW - 1.f) * 0.5f;
        float iy = ((crd[half][1] + 1.f) * HH - 1.f) * 0.5f;
        float iz = ((crd[half][2] + 1.f) * FF - 1.f) * 0.5f;
        float x0f = floorf(ix), y0f = floorf(iy), z0f = floorf(iz);
        float tx = ix - x0f, ty = iy - y0f, tz = iz - z0f;
        int x0 = (int)x0f, y0 = (int)y0f, z0 = (int)z0f;
        const float* vol = x + (size_t)(b * DIMC + g * CPG + t) * PQ;
        float acc = 0.f;
        #pragma unroll
        for (int dz = 0; dz < 2; ++dz) {
            int zc = z0 + dz;
            if (zc < 0 || zc >= FF) continue;
            float wz = dz ? tz : 1.f - tz;
            #pragma unroll
            for (int dy = 0; dy < 2; ++dy) {
                int yc = y0 + dy;
                if (yc < 0 || yc >= HH) continue;
                float wy = dy ? ty : 1.f - ty;
                #pragma unroll
                for (int dx = 0; dx < 2; ++dx) {
                    int xc = x0 + dx;
                    if (xc < 0 || xc >= WW) continue;
                    float wgt = wz * wy * (dx ? tx : 1.f - tx);
                    acc += vol[(zc * HH + yc) * WW + xc] * wgt;
                }
            }
        }
        kvs[half][t] = acc;
    }
    __syncthreads();

    const float* wkp = wk + (size_t)(g * ODIM + t) * CPG;
    const float* wvp = wv + (size_t)(g * ODIM + t) * CPG;
    float ak = 0.f, av = 0.f;
    #pragma unroll
    for (int i = 0; i < 64; i += 4) {
        float4 kv4 = *(const float4*)&kvs[half][i];
        float4 wk4 = *(const float4*)&wkp[i];
        float4 wv4 = *(const float4*)&wvp[i];
        ak += kv4.x * wk4.x + kv4.y * wk4.y + kv4.z * wk4.z + kv4.w * wk4.w;
        av += kv4.x * wv4.x + kv4.y * wv4.y + kv4.z * wv4.z + kv4.w * wv4.w;
    }
    kk2[((size_t)(bg * 64 + (t & 63)) * PJ + j) * 2 + (t >> 6)] = ak;
    vvT2[((size_t)(bg * 64 + (j >> 1)) * ODIM + t) * 2 + (j & 1)] = av;
}

// ---- fused CPB (MFMA, bias to LDS) + QK^T + softmax + attn*V; 8 queries/block
// LDS slimmed: per-mt (16-row) wave-private transpose (2176 B/wave) aliased with
// phase-B attL/qsL -> ~20.6 KB total, LDS no longer the occupancy limiter.
__global__ __launch_bounds__(256) void k_cpa(
    const float* __restrict__ q, const float* __restrict__ kk2,
    const float* __restrict__ vvT2, const float* __restrict__ gkv,
    const float* __restrict__ w0, const float* __restrict__ b0,
    const float* __restrict__ w1, const float* __restrict__ b1,
    const float* __restrict__ w2, const float* __restrict__ b2,
    float* __restrict__ outh) {
    // sbuf: phase A = 4 waves x 544 floats (16 rows x 17 f32x2) = 8704 B
    //       phase B = attL[2048] + qsL[1024] floats = 12288 B
    __shared__ __align__(16) float sbuf[3072];
    __shared__ __align__(16) float biasL[8 * 256];   // 8 KB
    __shared__ float redA[32];
    float* attL = sbuf;              // phase B
    float* qsL  = sbuf + 2048;       // phase B

    int blk = blockIdx.x;            // bg*128 + it
    int it = blk & 127, bg = blk >> 7;
    int b = bg >> 2, g = bg & 3;
    int tid = threadIdx.x;
    int w = tid >> 6, lane = tid & 63, col = lane & 15, quad = lane >> 4;

    // ---------------- phase A: CPB (barrier-free per wave) ----------------
    uint4 bfr[2][4];
    #pragma unroll
    for (int kc = 0; kc < 2; ++kc)
        #pragma unroll
        for (int nt = 0; nt < 4; ++nt) {
            int n = nt * 16 + col;
            int kbase = kc * 32 + quad * 8;
            unsigned int pk[4];
            #pragma unroll
            for (int p = 0; p < 4; ++p) {
                unsigned int lo = bfbits(w1[(kbase + 2 * p) * 64 + n]);
                unsigned int hi = bfbits(w1[(kbase + 2 * p + 1) * 64 + n]);
                pk[p] = lo | (hi << 16);
            }
            bfr[kc][nt] = make_uint4(pk[0], pk[1], pk[2], pk[3]);
        }

    float g0r[8], g1r[8], g2r[8];
    #pragma unroll
    for (int mtg = 0; mtg < 8; ++mtg) {
        int jr = mtg * 16 + col;
        g0r[mtg] = gkv[(bg * PJ + jr) * 3 + 0];
        g1r[mtg] = gkv[(bg * PJ + jr) * 3 + 1];
        g2r[mtg] = gkv[(bg * PJ + jr) * 3 + 2];
    }
    float b1v[4]; f32x2 w2v[4];
    #pragma unroll
    for (int nt = 0; nt < 4; ++nt) {
        int jj = nt * 16 + col;
        b1v[nt] = b1[jj];
        w2v[nt] = *(const f32x2*)&w2[jj * 2];
    }
    f32x2 bias_b2 = *(const f32x2*)b2;
    f32x2* mytb = (f32x2*)&sbuf[w * 544];   // 16 rows x 17 f32x2, wave-private

    #pragma unroll 1
    for (int ii = 0; ii < 2; ++ii) {
        int il = w * 2 + ii;
        int i = it * 8 + il;
        int wq_ = i & 15, hq = (i >> 4) & 15, fq = i >> 8;
        float cq0 = 2.f * fq / 3.f - 1.f;
        float cq1 = 2.f * hq / 15.f - 1.f;
        float cq2 = 2.f * wq_ / 15.f - 1.f;

        #pragma unroll 1
        for (int mh = 0; mh < 2; ++mh) {
            float t0[4], t1[4], t2[4];
            #pragma unroll
            for (int mt = 0; mt < 4; ++mt) {
                int mtg = mh * 4 + mt;
                float p0 = cq0 - g0r[mtg];
                float p1 = cq1 - g1r[mtg];
                float p2 = cq2 - g2r[mtg];
                t0[mt] = copysignf(__logf(1.f + fabsf(p0)), p0);
                t1[mt] = copysignf(__logf(1.f + fabsf(p1)), p1);
                t2[mt] = copysignf(__logf(1.f + fabsf(p2)), p2);
            }
            f32x4 acc[4][4] = {};
            #pragma unroll
            for (int kc = 0; kc < 2; ++kc) {
                int d0 = kc * 32 + quad * 8;
                f32x2 w0a[4], w0b[4], w0c[4], b0p[4];
                #pragma unroll
                for (int pr = 0; pr < 4; ++pr) {
                    w0a[pr] = *(const f32x2*)&w0[d0 + 2 * pr];
                    w0b[pr] = *(const f32x2*)&w0[64 + d0 + 2 * pr];
                    w0c[pr] = *(const f32x2*)&w0[128 + d0 + 2 * pr];
                    b0p[pr] = *(const f32x2*)&b0[d0 + 2 * pr];
                }
                #pragma unroll
                for (int mt = 0; mt < 4; ++mt) {
                    unsigned int pk[4];
                    #pragma unroll
                    for (int pr = 0; pr < 4; ++pr) {
                        f32x2 z = b0p[pr];
                        z += t0[mt] * w0a[pr];
                        z += t1[mt] * w0b[pr];
                        z += t2[mt] * w0c[pr];
                        z.x = fmaxf(z.x, 0.f); z.y = fmaxf(z.y, 0.f);
                        pk[pr] = pack_bf2(z);
                    }
                    uint4 afu = make_uint4(pk[0], pk[1], pk[2], pk[3]);
                    bf16x8 af = *(bf16x8*)&afu;
                    #pragma unroll
                    for (int nt = 0; nt < 4; ++nt)
                        acc[mt][nt] = __builtin_amdgcn_mfma_f32_16x16x32_bf16(
                            af, *(bf16x8*)&bfr[kc][nt], acc[mt][nt], 0, 0, 0);
                }
            }
            // epilogue: per-mt 16-row stage + in-wave consume (no barriers)
            f32x2 s = bias_b2;
            #pragma unroll
            for (int mt = 0; mt < 4; ++mt) {
                #pragma unroll
                for (int reg = 0; reg < 4; ++reg) {
                    f32x2 pp = {0.f, 0.f};
                    #pragma unroll
                    for (int nt = 0; nt < 4; ++nt) {
                        float hv = fmaxf(acc[mt][nt][reg] + b1v[nt], 0.f);
                        pp += hv * w2v[nt];
                    }
                    mytb[(quad * 4 + reg) * 17 + col] = pp;
                }
                if ((lane >> 4) == mt) {
                    const f32x2* pr2 = mytb + (lane & 15) * 17;
                    #pragma unroll
                    for (int c = 0; c < 16; ++c) s += pr2[c];
                }
            }
            int jl = mh * 64 + lane;
            *(f32x2*)&biasL[(il * 128 + jl) * 2] = s;
        }
    }
    __syncthreads();   // phase A complete; sbuf now reusable as attL/qsL

    // ---------------- phase B: attention for 8 queries ----------------
    int half = tid >> 7;             // i-half (4 queries each)
    int j = tid & 127;               // also channel index

    {
        const float* qp = q + (size_t)(bg * ODIM + j) * PQ + it * 8 + half * 4;
        float4 qa = *(const float4*)qp;
        int e = j >> 6, d = j & 63;
        qsL[(half * 4 + 0) * 128 + d * 2 + e] = qa.x * 0.125f;
        qsL[(half * 4 + 1) * 128 + d * 2 + e] = qa.y * 0.125f;
        qsL[(half * 4 + 2) * 128 + d * 2 + e] = qa.z * 0.125f;
        qsL[(half * 4 + 3) * 128 + d * 2 + e] = qa.w * 0.125f;
    }
    __syncthreads();

    f32x2 sc[4];
    #pragma unroll
    for (int k = 0; k < 4; ++k)
        sc[k] = *(const f32x2*)&biasL[((half * 4 + k) * 128 + j) * 2];

    {
        const f32x2* kp = (const f32x2*)kk2 + (size_t)(bg * 64) * PJ + j;
        const f32x2* qs2 = (const f32x2*)qsL;
        #pragma unroll 4
        for (int d = 0; d < 64; ++d) {
            f32x2 kv2 = kp[(size_t)d * PJ];
            #pragma unroll
            for (int k = 0; k < 4; ++k)
                sc[k] += qs2[(half * 4 + k) * 64 + d] * kv2;
        }
    }
    // attL [0..2048) does not overlap qsL [2048..3072) or biasL -> no barrier needed here
    #pragma unroll
    for (int k = 0; k < 4; ++k) {
        int il = half * 4 + k;
        attL[il * 256 + j] = sc[k].x;
        attL[il * 256 + 128 + j] = sc[k].y;
    }
    __syncthreads();

    // softmax: 16 rows (il, head); wave w handles rows w*4..w*4+3
    #pragma unroll
    for (int rr = 0; rr < 4; ++rr) {
        int r = w * 4 + rr;
        int il = r >> 1, hd = r & 1;
        float a0 = attL[il * 256 + hd * 128 + lane];
        float a1 = attL[il * 256 + hd * 128 + 64 + lane];
        float mx = fmaxf(a0, a1);
        #pragma unroll
        for (int off = 32; off; off >>= 1) mx = fmaxf(mx, __shfl_xor(mx, off));
        float ex = __expf(a0 - mx) + __expf(a1 - mx);
        #pragma unroll
        for (int off = 32; off; off >>= 1) ex += __shfl_xor(ex, off);
        if (lane == 0) { redA[r * 2] = mx; redA[r * 2 + 1] = ex; }
    }
    __syncthreads();
    #pragma unroll
    for (int k = 0; k < 4; ++k) {
        int il = half * 4 + k;
        float p0n = __expf(sc[k].x - redA[(il * 2 + 0) * 2]) * (1.f / redA[(il * 2 + 0) * 2 + 1]);
        float p1n = __expf(sc[k].y - redA[(il * 2 + 1) * 2]) * (1.f / redA[(il * 2 + 1) * 2 + 1]);
        attL[il * 256 + j] = p0n;
        attL[il * 256 + 128 + j] = p1n;
    }
    __syncthreads();

    // attn * V: thread (half, ch=j) computes 4 i's of channel j
    {
        const f32x2* vp = (const f32x2*)vvT2 + (size_t)(bg * 64) * ODIM + j;
        int e = j >> 6;
        f32x2 oacc[4] = {};
        #pragma unroll 4
        for (int jp = 0; jp < 64; ++jp) {
            f32x2 vv2 = vp[(size_t)jp * ODIM];
            #pragma unroll
            for (int k = 0; k < 4; ++k) {
                f32x2 ap2 = *(const f32x2*)&attL[(half * 4 + k) * 256 + e * 128 + jp * 2];
                oacc[k] += ap2 * vv2;
            }
        }
        #pragma unroll
        for (int k = 0; k < 4; ++k)
            outh[((size_t)b * PQ + it * 8 + half * 4 + k) * INNERC + g * 128 + j] =
                oacc[k].x + oacc[k].y;
    }
}

// ---- final projection: LDS-tiled fp32 GEMM. M=2048 (b*p), N=256 (o), K=512.
__global__ __launch_bounds__(256) void k_out(
    const float* __restrict__ outh, const float* __restrict__ wo,
    const float* __restrict__ bo, float* __restrict__ out) {
    __shared__ float At[32][68];
    __shared__ float Bt[32][36];
    int blk = blockIdx.x;            // 0..255
    int nt = blk & 7, mt = blk >> 3;
    int m0 = mt * 64, o0 = nt * 32;
    int tid = threadIdx.x;
    int tm = tid >> 4, tn = tid & 15;
    int mloc = tm * 4, nloc = tn * 2;

    int ra = tid >> 2, ca = (tid & 3) * 8;
    int rb = tid >> 3, cb = (tid & 7) * 4;

    float4 pa0, pa1, pb;
    {
        const float* Ap = outh + (size_t)(m0 + ra) * INNERC + ca;
        pa0 = *(const float4*)Ap;
        pa1 = *(const float4*)(Ap + 4);
        pb = *(const float4*)(wo + (size_t)(o0 + rb) * INNERC + cb);
    }

    float acc[4][2] = {};
    for (int ch = 0; ch < 16; ++ch) {
        #pragma unroll
        for (int k = 0; k < 4; ++k) {
            At[ca + k][ra] = ((const float*)&pa0)[k];
            At[ca + 4 + k][ra] = ((const float*)&pa1)[k];
            Bt[cb + k][rb] = ((const float*)&pb)[k];
        }
        __syncthreads();
        if (ch < 15) {
            int c0 = (ch + 1) * 32;
            const float* Ap = outh + (size_t)(m0 + ra) * INNERC + c0 + ca;
            pa0 = *(const float4*)Ap;
            pa1 = *(const float4*)(Ap + 4);
            pb = *(const float4*)(wo + (size_t)(o0 + rb) * INNERC + c0 + cb);
        }
        #pragma unroll
        for (int kk = 0; kk < 32; ++kk) {
            float4 a4 = *(const float4*)&At[kk][mloc];
            float2 b2 = *(const float2*)&Bt[kk][nloc];
            #pragma unroll
            for (int i = 0; i < 4; ++i) {
                float av = ((const float*)&a4)[i];
                acc[i][0] += av * b2.x;
                acc[i][1] += av * b2.y;
            }
        }
        __syncthreads();
    }

    #pragma unroll
    for (int jn = 0; jn < 2; ++jn) {
        int o = o0 + nloc + jn;
        float bv = bo[o];
        #pragma unroll
        for (int i = 0; i < 4; ++i) {
            int m = m0 + mloc + i;
            int b = m >> 10, p = m & 1023;
            out[((size_t)(b * DIMC + o)) * PQ + p] = acc[i][jn] + bv;
        }
    }
}

extern "C" void kernel_launch(void* const* d_in, const int* in_sizes, int n_in,
                              void* d_out, int out_size, void* d_ws, size_t ws_size,
                              hipStream_t stream) {
    const float* x   = (const float*)d_in[0];
    const float* wq  = (const float*)d_in[1];
    const float* wk  = (const float*)d_in[2];
    const float* wv  = (const float*)d_in[3];
    const float* dww = (const float*)d_in[4];
    const float* dwb = (const float*)d_in[5];
    const float* pw  = (const float*)d_in[6];
    const float* w0  = (const float*)d_in[7];
    const float* b0  = (const float*)d_in[8];
    const float* w1  = (const float*)d_in[9];
    const float* b1  = (const float*)d_in[10];
    const float* w2  = (const float*)d_in[11];
    const float* b2  = (const float*)d_in[12];
    const float* wo  = (const float*)d_in[13];
    const float* bo  = (const float*)d_in[14];
    float* out = (float*)d_out;

    float* ws_f  = (float*)d_ws;
    float* q     = ws_f;                  // 1048576
    float* act   = q + 1048576;           // 131072
    float* gkv   = act + 131072;          // 3072
    float* kk2   = gkv + 3072;            // 131072
    float* vvT2  = kk2 + 131072;          // 131072
    float* outh  = vvT2 + 131072;         // 1048576

    k_qdw<<<256, 512, 0, stream>>>(x, wq, dww, dwb, q, act);
    k_kvf<<<512, 256, 0, stream>>>(act, pw, x, wk, wv, gkv, kk2, vvT2);
    k_cpa<<<1024, 256, 0, stream>>>(q, kk2, vvT2, gkv, w0, b0, w1, b1, w2, b2, outh);
    k_out<<<256, 256, 0, stream>>>(outh, wo, bo, out);
}

// Round 14
// 171.706 us; speedup vs baseline: 1.2701x; 1.2701x over previous
//
#include <hip/hip_runtime.h>
#include <hip/hip_bf16.h>
#include <math.h>

#define BB 2
#define DIMC 256
#define FF 4
#define HH 16
#define WW 16
#define GRP 4
#define CPG 64        // DIM/GROUPS
#define ODIM 128      // OFF_DIMS
#define PQ 1024       // F*H*W
#define PJ 128        // FD*HD*WD
#define NBG 8         // B*GROUPS
#define INNERC 512

typedef short bf16x8 __attribute__((ext_vector_type(8)));
typedef float f32x4 __attribute__((ext_vector_type(4)));
typedef float f32x2 __attribute__((ext_vector_type(2)));

__device__ __forceinline__ unsigned int bfbits(float x) {
    union { float f; unsigned int u; } v; v.f = x;
    unsigned int u = v.u;
    unsigned int r = u + 0x7fffu + ((u >> 16) & 1u);
    return r >> 16;
}

__device__ __forceinline__ unsigned int pack_bf2(f32x2 a) {
    float2 ff = make_float2(a.x, a.y);
    __hip_bfloat162 h2 = __float22bfloat162_rn(ff);
    union { __hip_bfloat162 h; unsigned int u; } c; c.h = h2;
    return c.u;
}

// ---- fused: q = grouped 1x1 conv (LDS-resident) -> depthwise conv + GELU
__global__ __launch_bounds__(512) void k_qdw(
    const float* __restrict__ x, const float* __restrict__ wq,
    const float* __restrict__ dww, const float* __restrict__ dwb,
    float* __restrict__ q, float* __restrict__ act) {
    __shared__ float qs[1024 * 4];   // qs[p][k] : 16 KB
    int og = blockIdx.x & 31, bg = blockIdx.x >> 5;
    int b = bg >> 2, g = bg & 3;
    int o0 = og * 4;
    int tid = threadIdx.x;           // 0..511
    const float* xp = x + (size_t)(b * DIMC + g * CPG) * PQ;
    const float* wp = wq + (size_t)(g * ODIM + o0) * CPG;

    float accq[2][4] = {};
    #pragma unroll 8
    for (int i = 0; i < CPG; ++i) {
        float wv[4];
        #pragma unroll
        for (int k = 0; k < 4; ++k) wv[k] = wp[k * CPG + i];
        #pragma unroll
        for (int pi = 0; pi < 2; ++pi) {
            float xv = xp[(size_t)i * PQ + tid + pi * 512];
            #pragma unroll
            for (int k = 0; k < 4; ++k) accq[pi][k] += xv * wv[k];
        }
    }
    #pragma unroll
    for (int pi = 0; pi < 2; ++pi) {
        int p = tid + pi * 512;
        *(float4*)&qs[p * 4] = make_float4(accq[pi][0], accq[pi][1], accq[pi][2], accq[pi][3]);
        #pragma unroll
        for (int k = 0; k < 4; ++k)
            q[(size_t)(bg * ODIM + o0 + k) * PQ + p] = accq[pi][k];
    }
    __syncthreads();

    {
        int cl = tid & 3, j = tid >> 2;   // 512 units = 128 j x 4 c
        int c = o0 + cl;
        int xo = j & 7, yo = (j >> 3) & 7, zo = j >> 6;
        const float* wd = dww + c * 64;
        float acc = dwb[c];
        #pragma unroll
        for (int kz = 0; kz < 4; ++kz) {
            int z = 2 * zo - 1 + kz;
            if (z < 0 || z >= FF) continue;
            #pragma unroll
            for (int ky = 0; ky < 4; ++ky) {
                int y = 2 * yo - 1 + ky;
                if (y < 0 || y >= HH) continue;
                #pragma unroll
                for (int kx = 0; kx < 4; ++kx) {
                    int xx = 2 * xo - 1 + kx;
                    if (xx < 0 || xx >= WW) continue;
                    acc += qs[((z * HH + y) * WW + xx) * 4 + cl] * wd[(kz * 4 + ky) * 4 + kx];
                }
            }
        }
        act[((size_t)bg * PJ + j) * ODIM + c] =
            0.5f * acc * (1.0f + erff(acc * 0.70710678118654752f));
    }
}

// ------- fused offsets -> grid -> trilinear sample -> k/v proj; 2 j's per block
__global__ __launch_bounds__(256) void k_kvf(
    const float* __restrict__ act, const float* __restrict__ pw,
    const float* __restrict__ x, const float* __restrict__ wk,
    const float* __restrict__ wv, float* __restrict__ gkv,
    float* __restrict__ kk2, float* __restrict__ vvT2) {
    __shared__ float red2[2][6];
    __shared__ float crd[2][3];
    __shared__ float kvs[2][64];
    int blk = blockIdx.x;            // bg*64 + jt
    int jt = blk & 63, bg = blk >> 6;
    int b = bg >> 2, g = bg & 3;
    int tid = threadIdx.x;
    int half = tid >> 7;
    int t = tid & 127;
    int j = jt * 2 + half;
    int wv_ = t >> 6;

    float val = act[((size_t)bg * PJ + j) * ODIM + t];
    float s0 = val * pw[t];
    float s1 = val * pw[ODIM + t];
    float s2 = val * pw[2 * ODIM + t];
    #pragma unroll
    for (int off = 32; off; off >>= 1) {
        s0 += __shfl_xor(s0, off);
        s1 += __shfl_xor(s1, off);
        s2 += __shfl_xor(s2, off);
    }
    if ((t & 63) == 0) {
        red2[half][wv_ * 3] = s0; red2[half][wv_ * 3 + 1] = s1; red2[half][wv_ * 3 + 2] = s2;
    }
    __syncthreads();
    if (t == 0) {
        s0 = red2[half][0] + red2[half][3];
        s1 = red2[half][1] + red2[half][4];
        s2 = red2[half][2] + red2[half][5];
        float xo = (float)(j & 7), yo = (float)((j >> 3) & 7), zo = (float)(j >> 6);
        float vf = zo + 2.f * tanhf(s0);
        float vh = yo + 2.f * tanhf(s1);
        float vw = xo + 2.f * tanhf(s2);
        float c0 = 2.f * vf - 1.f;
        float c1 = 2.f * vh / 7.f - 1.f;
        float c2 = 2.f * vw / 7.f - 1.f;
        crd[half][0] = c0; crd[half][1] = c1; crd[half][2] = c2;
        gkv[(bg * PJ + j) * 3 + 0] = c0;
        gkv[(bg * PJ + j) * 3 + 1] = c1;
        gkv[(bg * PJ + j) * 3 + 2] = c2;
    }
    __syncthreads();

    // BUG-COMPATIBLE: crd[0] (f-coord) -> x/W axis, crd[1] -> y/H, crd[2] (w) -> z/D.
    if (t < 64) {
        float ix = ((crd[half][0] + 1.f) * WW - 1.f) * 0.5f;
        float iy = ((crd[half][1] + 1.f) * HH - 1.f) * 0.5f;
        float iz = ((crd[half][2] + 1.f) * FF - 1.f) * 0.5f;
        float x0f = floorf(ix), y0f = floorf(iy), z0f = floorf(iz);
        float tx = ix - x0f, ty = iy - y0f, tz = iz - z0f;
        int x0 = (int)x0f, y0 = (int)y0f, z0 = (int)z0f;
        const float* vol = x + (size_t)(b * DIMC + g * CPG + t) * PQ;
        float acc = 0.f;
        #pragma unroll
        for (int dz = 0; dz < 2; ++dz) {
            int zc = z0 + dz;
            if (zc < 0 || zc >= FF) continue;
            float wz = dz ? tz : 1.f - tz;
            #pragma unroll
            for (int dy = 0; dy < 2; ++dy) {
                int yc = y0 + dy;
                if (yc < 0 || yc >= HH) continue;
                float wy = dy ? ty : 1.f - ty;
                #pragma unroll
                for (int dx = 0; dx < 2; ++dx) {
                    int xc = x0 + dx;
                    if (xc < 0 || xc >= WW) continue;
                    float wgt = wz * wy * (dx ? tx : 1.f - tx);
                    acc += vol[(zc * HH + yc) * WW + xc] * wgt;
                }
            }
        }
        kvs[half][t] = acc;
    }
    __syncthreads();

    const float* wkp = wk + (size_t)(g * ODIM + t) * CPG;
    const float* wvp = wv + (size_t)(g * ODIM + t) * CPG;
    float ak = 0.f, av = 0.f;
    #pragma unroll
    for (int i = 0; i < 64; i += 4) {
        float4 kv4 = *(const float4*)&kvs[half][i];
        float4 wk4 = *(const float4*)&wkp[i];
        float4 wv4 = *(const float4*)&wvp[i];
        ak += kv4.x * wk4.x + kv4.y * wk4.y + kv4.z * wk4.z + kv4.w * wk4.w;
        av += kv4.x * wv4.x + kv4.y * wv4.y + kv4.z * wv4.z + kv4.w * wv4.w;
    }
    kk2[((size_t)(bg * 64 + (t & 63)) * PJ + j) * 2 + (t >> 6)] = ak;
    vvT2[((size_t)(bg * 64 + (j >> 1)) * ODIM + t) * 2 + (j & 1)] = av;
}

// ---- fused CPB (MFMA, bias to LDS) + QK^T + softmax + attn*V; 16 queries/block
// R10 structure (best known: 62 us); ii loop pinned no-unroll; phase-B unroll 4
__global__ __launch_bounds__(256) void k_cpa(
    const float* __restrict__ q, const float* __restrict__ kk2,
    const float* __restrict__ vvT2, const float* __restrict__ gkv,
    const float* __restrict__ w0, const float* __restrict__ b0,
    const float* __restrict__ w1, const float* __restrict__ b1,
    const float* __restrict__ w2, const float* __restrict__ b2,
    float* __restrict__ outh) {
    __shared__ __align__(16) float tbuf[4 * 2176];   // 34816 B; phase-B alias below
    __shared__ __align__(16) float biasL[16 * 256];  // [il][j]*2 heads interleaved: 16 KB
    __shared__ float redA[64];
    float* attL = tbuf;              // 16*256 floats
    float* qsL  = tbuf + 4096;       // 16*128 floats

    int blk = blockIdx.x;            // bg*64 + it
    int it = blk & 63, bg = blk >> 6;
    int b = bg >> 2, g = bg & 3;
    int tid = threadIdx.x;
    int w = tid >> 6, lane = tid & 63, col = lane & 15, quad = lane >> 4;

    // ---------------- phase A: CPB (barrier-free per wave) ----------------
    uint4 bfr[2][4];
    #pragma unroll
    for (int kc = 0; kc < 2; ++kc)
        #pragma unroll
        for (int nt = 0; nt < 4; ++nt) {
            int n = nt * 16 + col;
            int kbase = kc * 32 + quad * 8;
            unsigned int pk[4];
            #pragma unroll
            for (int p = 0; p < 4; ++p) {
                unsigned int lo = bfbits(w1[(kbase + 2 * p) * 64 + n]);
                unsigned int hi = bfbits(w1[(kbase + 2 * p + 1) * 64 + n]);
                pk[p] = lo | (hi << 16);
            }
            bfr[kc][nt] = make_uint4(pk[0], pk[1], pk[2], pk[3]);
        }

    float g0r[8], g1r[8], g2r[8];
    #pragma unroll
    for (int mtg = 0; mtg < 8; ++mtg) {
        int jr = mtg * 16 + col;
        g0r[mtg] = gkv[(bg * PJ + jr) * 3 + 0];
        g1r[mtg] = gkv[(bg * PJ + jr) * 3 + 1];
        g2r[mtg] = gkv[(bg * PJ + jr) * 3 + 2];
    }
    float b1v[4]; f32x2 w2v[4];
    #pragma unroll
    for (int nt = 0; nt < 4; ++nt) {
        int jj = nt * 16 + col;
        b1v[nt] = b1[jj];
        w2v[nt] = *(const f32x2*)&w2[jj * 2];
    }
    f32x2 bias_b2 = *(const f32x2*)b2;
    f32x2* mytb = (f32x2*)&tbuf[w * 2176];

    #pragma unroll 1
    for (int ii = 0; ii < 4; ++ii) {
        int il = w * 4 + ii;
        int i = it * 16 + il;
        int wq_ = i & 15, hq = (i >> 4) & 15, fq = i >> 8;
        float cq0 = 2.f * fq / 3.f - 1.f;
        float cq1 = 2.f * hq / 15.f - 1.f;
        float cq2 = 2.f * wq_ / 15.f - 1.f;

        #pragma unroll 1
        for (int mh = 0; mh < 2; ++mh) {
            float t0[4], t1[4], t2[4];
            #pragma unroll
            for (int mt = 0; mt < 4; ++mt) {
                int mtg = mh * 4 + mt;
                float p0 = cq0 - g0r[mtg];
                float p1 = cq1 - g1r[mtg];
                float p2 = cq2 - g2r[mtg];
                t0[mt] = copysignf(__logf(1.f + fabsf(p0)), p0);
                t1[mt] = copysignf(__logf(1.f + fabsf(p1)), p1);
                t2[mt] = copysignf(__logf(1.f + fabsf(p2)), p2);
            }
            f32x4 acc[4][4] = {};
            #pragma unroll
            for (int kc = 0; kc < 2; ++kc) {
                int d0 = kc * 32 + quad * 8;
                f32x2 w0a[4], w0b[4], w0c[4], b0p[4];
                #pragma unroll
                for (int pr = 0; pr < 4; ++pr) {
                    w0a[pr] = *(const f32x2*)&w0[d0 + 2 * pr];
                    w0b[pr] = *(const f32x2*)&w0[64 + d0 + 2 * pr];
                    w0c[pr] = *(const f32x2*)&w0[128 + d0 + 2 * pr];
                    b0p[pr] = *(const f32x2*)&b0[d0 + 2 * pr];
                }
                #pragma unroll
                for (int mt = 0; mt < 4; ++mt) {
                    unsigned int pk[4];
                    #pragma unroll
                    for (int pr = 0; pr < 4; ++pr) {
                        f32x2 z = b0p[pr];
                        z += t0[mt] * w0a[pr];
                        z += t1[mt] * w0b[pr];
                        z += t2[mt] * w0c[pr];
                        z.x = fmaxf(z.x, 0.f); z.y = fmaxf(z.y, 0.f);
                        pk[pr] = pack_bf2(z);
                    }
                    uint4 afu = make_uint4(pk[0], pk[1], pk[2], pk[3]);
                    bf16x8 af = *(bf16x8*)&afu;
                    #pragma unroll
                    for (int nt = 0; nt < 4; ++nt)
                        acc[mt][nt] = __builtin_amdgcn_mfma_f32_16x16x32_bf16(
                            af, *(bf16x8*)&bfr[kc][nt], acc[mt][nt], 0, 0, 0);
                }
            }
            #pragma unroll
            for (int mt = 0; mt < 4; ++mt)
                #pragma unroll
                for (int reg = 0; reg < 4; ++reg) {
                    f32x2 pp = {0.f, 0.f};
                    #pragma unroll
                    for (int nt = 0; nt < 4; ++nt) {
                        float hv = fmaxf(acc[mt][nt][reg] + b1v[nt], 0.f);
                        pp += hv * w2v[nt];
                    }
                    mytb[(mt * 16 + quad * 4 + reg) * 17 + col] = pp;
                }
            f32x2 s = bias_b2;
            {
                const f32x2* pr2 = mytb + lane * 17;
                #pragma unroll
                for (int c = 0; c < 16; ++c) s += pr2[c];
            }
            int jl = mh * 64 + lane;
            *(f32x2*)&biasL[(il * 128 + jl) * 2] = s;
        }
    }
    __syncthreads();   // phase A complete; tbuf now reusable as attL/qsL

    // ---------------- phase B: attention for 16 queries ----------------
    int half = tid >> 7;             // i-half (8 queries each)
    int j = tid & 127;               // also channel index in AV

    {
        const float* qp = q + (size_t)(bg * ODIM + j) * PQ + it * 16 + half * 8;
        float4 qa = *(const float4*)qp;
        float4 qb = *(const float4*)(qp + 4);
        int e = j >> 6, d = j & 63;
        qsL[(half * 8 + 0) * 128 + d * 2 + e] = qa.x * 0.125f;
        qsL[(half * 8 + 1) * 128 + d * 2 + e] = qa.y * 0.125f;
        qsL[(half * 8 + 2) * 128 + d * 2 + e] = qa.z * 0.125f;
        qsL[(half * 8 + 3) * 128 + d * 2 + e] = qa.w * 0.125f;
        qsL[(half * 8 + 4) * 128 + d * 2 + e] = qb.x * 0.125f;
        qsL[(half * 8 + 5) * 128 + d * 2 + e] = qb.y * 0.125f;
        qsL[(half * 8 + 6) * 128 + d * 2 + e] = qb.z * 0.125f;
        qsL[(half * 8 + 7) * 128 + d * 2 + e] = qb.w * 0.125f;
    }
    __syncthreads();

    f32x2 sc[8];
    #pragma unroll
    for (int k = 0; k < 8; ++k)
        sc[k] = *(const f32x2*)&biasL[((half * 8 + k) * 128 + j) * 2];

    {
        const f32x2* kp = (const f32x2*)kk2 + (size_t)(bg * 64) * PJ + j;
        const f32x2* qs2 = (const f32x2*)qsL;
        #pragma unroll 4
        for (int d = 0; d < 64; ++d) {
            f32x2 kv2 = kp[(size_t)d * PJ];
            #pragma unroll
            for (int k = 0; k < 8; ++k)
                sc[k] += qs2[(half * 8 + k) * 64 + d] * kv2;
        }
    }
    #pragma unroll
    for (int k = 0; k < 8; ++k) {
        int il = half * 8 + k;
        attL[il * 256 + j] = sc[k].x;
        attL[il * 256 + 128 + j] = sc[k].y;
    }
    __syncthreads();

    // softmax: 32 rows (il, head); wave w handles rows w*8..w*8+7
    #pragma unroll
    for (int rr = 0; rr < 8; ++rr) {
        int r = w * 8 + rr;
        int il = r >> 1, hd = r & 1;
        float a0 = attL[il * 256 + hd * 128 + lane];
        float a1 = attL[il * 256 + hd * 128 + 64 + lane];
        float mx = fmaxf(a0, a1);
        #pragma unroll
        for (int off = 32; off; off >>= 1) mx = fmaxf(mx, __shfl_xor(mx, off));
        float ex = __expf(a0 - mx) + __expf(a1 - mx);
        #pragma unroll
        for (int off = 32; off; off >>= 1) ex += __shfl_xor(ex, off);
        if (lane == 0) { redA[r * 2] = mx; redA[r * 2 + 1] = ex; }
    }
    __syncthreads();
    #pragma unroll
    for (int k = 0; k < 8; ++k) {
        int il = half * 8 + k;
        float p0n = __expf(sc[k].x - redA[(il * 2 + 0) * 2]) * (1.f / redA[(il * 2 + 0) * 2 + 1]);
        float p1n = __expf(sc[k].y - redA[(il * 2 + 1) * 2]) * (1.f / redA[(il * 2 + 1) * 2 + 1]);
        attL[il * 256 + j] = p0n;
        attL[il * 256 + 128 + j] = p1n;
    }
    __syncthreads();

    // attn * V: thread (half, ch=j) computes 8 i's of channel j
    {
        const f32x2* vp = (const f32x2*)vvT2 + (size_t)(bg * 64) * ODIM + j;
        int e = j >> 6;
        f32x2 oacc[8] = {};
        #pragma unroll 4
        for (int jp = 0; jp < 64; ++jp) {
            f32x2 vv2 = vp[(size_t)jp * ODIM];
            #pragma unroll
            for (int k = 0; k < 8; ++k) {
                f32x2 ap2 = *(const f32x2*)&attL[(half * 8 + k) * 256 + e * 128 + jp * 2];
                oacc[k] += ap2 * vv2;
            }
        }
        #pragma unroll
        for (int k = 0; k < 8; ++k)
            outh[((size_t)b * PQ + it * 16 + half * 8 + k) * INNERC + g * 128 + j] =
                oacc[k].x + oacc[k].y;
    }
}

// ---- final projection: LDS-tiled fp32 GEMM. M=2048 (b*p), N=256 (o), K=512.
__global__ __launch_bounds__(256) void k_out(
    const float* __restrict__ outh, const float* __restrict__ wo,
    const float* __restrict__ bo, float* __restrict__ out) {
    __shared__ float At[32][68];
    __shared__ float Bt[32][36];
    int blk = blockIdx.x;            // 0..255
    int nt = blk & 7, mt = blk >> 3;
    int m0 = mt * 64, o0 = nt * 32;
    int tid = threadIdx.x;
    int tm = tid >> 4, tn = tid & 15;
    int mloc = tm * 4, nloc = tn * 2;

    int ra = tid >> 2, ca = (tid & 3) * 8;
    int rb = tid >> 3, cb = (tid & 7) * 4;

    float4 pa0, pa1, pb;
    {
        const float* Ap = outh + (size_t)(m0 + ra) * INNERC + ca;
        pa0 = *(const float4*)Ap;
        pa1 = *(const float4*)(Ap + 4);
        pb = *(const float4*)(wo + (size_t)(o0 + rb) * INNERC + cb);
    }

    float acc[4][2] = {};
    for (int ch = 0; ch < 16; ++ch) {
        #pragma unroll
        for (int k = 0; k < 4; ++k) {
            At[ca + k][ra] = ((const float*)&pa0)[k];
            At[ca + 4 + k][ra] = ((const float*)&pa1)[k];
            Bt[cb + k][rb] = ((const float*)&pb)[k];
        }
        __syncthreads();
        if (ch < 15) {
            int c0 = (ch + 1) * 32;
            const float* Ap = outh + (size_t)(m0 + ra) * INNERC + c0 + ca;
            pa0 = *(const float4*)Ap;
            pa1 = *(const float4*)(Ap + 4);
            pb = *(const float4*)(wo + (size_t)(o0 + rb) * INNERC + c0 + cb);
        }
        #pragma unroll
        for (int kk = 0; kk < 32; ++kk) {
            float4 a4 = *(const float4*)&At[kk][mloc];
            float2 b2 = *(const float2*)&Bt[kk][nloc];
            #pragma unroll
            for (int i = 0; i < 4; ++i) {
                float av = ((const float*)&a4)[i];
                acc[i][0] += av * b2.x;
                acc[i][1] += av * b2.y;
            }
        }
        __syncthreads();
    }

    #pragma unroll
    for (int jn = 0; jn < 2; ++jn) {
        int o = o0 + nloc + jn;
        float bv = bo[o];
        #pragma unroll
        for (int i = 0; i < 4; ++i) {
            int m = m0 + mloc + i;
            int b = m >> 10, p = m & 1023;
            out[((size_t)(b * DIMC + o)) * PQ + p] = acc[i][jn] + bv;
        }
    }
}

extern "C" void kernel_launch(void* const* d_in, const int* in_sizes, int n_in,
                              void* d_out, int out_size, void* d_ws, size_t ws_size,
                              hipStream_t stream) {
    const float* x   = (const float*)d_in[0];
    const float* wq  = (const float*)d_in[1];
    const float* wk  = (const float*)d_in[2];
    const float* wv  = (const float*)d_in[3];
    const float* dww = (const float*)d_in[4];
    const float* dwb = (const float*)d_in[5];
    const float* pw  = (const float*)d_in[6];
    const float* w0  = (const float*)d_in[7];
    const float* b0  = (const float*)d_in[8];
    const float* w1  = (const float*)d_in[9];
    const float* b1  = (const float*)d_in[10];
    const float* w2  = (const float*)d_in[11];
    const float* b2  = (const float*)d_in[12];
    const float* wo  = (const float*)d_in[13];
    const float* bo  = (const float*)d_in[14];
    float* out = (float*)d_out;

    float* ws_f  = (float*)d_ws;
    float* q     = ws_f;                  // 1048576
    float* act   = q + 1048576;           // 131072
    float* gkv   = act + 131072;          // 3072
    float* kk2   = gkv + 3072;            // 131072
    float* vvT2  = kk2 + 131072;          // 131072
    float* outh  = vvT2 + 131072;         // 1048576

    k_qdw<<<256, 512, 0, stream>>>(x, wq, dww, dwb, q, act);
    k_kvf<<<512, 256, 0, stream>>>(act, pw, x, wk, wv, gkv, kk2, vvT2);
    k_cpa<<<512, 256, 0, stream>>>(q, kk2, vvT2, gkv, w0, b0, w1, b1, w2, b2, outh);
    k_out<<<256, 256, 0, stream>>>(outh, wo, bo, out);
}

// Round 16
// 166.231 us; speedup vs baseline: 1.3119x; 1.0329x over previous
//
#include <hip/hip_runtime.h>
#include <hip/hip_bf16.h>
#include <hip/hip_fp16.h>
#include <math.h>

#define BB 2
#define DIMC 256
#define FF 4
#define HH 16
#define WW 16
#define GRP 4
#define CPG 64        // DIM/GROUPS
#define ODIM 128      // OFF_DIMS
#define PQ 1024       // F*H*W
#define PJ 128        // FD*HD*WD
#define NBG 8         // B*GROUPS
#define INNERC 512

typedef _Float16 f16x8 __attribute__((ext_vector_type(8)));
typedef _Float16 f16x2 __attribute__((ext_vector_type(2)));
typedef float f32x4 __attribute__((ext_vector_type(4)));
typedef float f32x2 __attribute__((ext_vector_type(2)));

// ---- fused: q = grouped 1x1 conv (LDS-resident) -> depthwise conv + GELU
__global__ __launch_bounds__(512) void k_qdw(
    const float* __restrict__ x, const float* __restrict__ wq,
    const float* __restrict__ dww, const float* __restrict__ dwb,
    float* __restrict__ q, float* __restrict__ act) {
    __shared__ float qs[1024 * 4];   // qs[p][k] : 16 KB
    int og = blockIdx.x & 31, bg = blockIdx.x >> 5;
    int b = bg >> 2, g = bg & 3;
    int o0 = og * 4;
    int tid = threadIdx.x;           // 0..511
    const float* xp = x + (size_t)(b * DIMC + g * CPG) * PQ;
    const float* wp = wq + (size_t)(g * ODIM + o0) * CPG;

    float accq[2][4] = {};
    #pragma unroll 8
    for (int i = 0; i < CPG; ++i) {
        float wv[4];
        #pragma unroll
        for (int k = 0; k < 4; ++k) wv[k] = wp[k * CPG + i];
        #pragma unroll
        for (int pi = 0; pi < 2; ++pi) {
            float xv = xp[(size_t)i * PQ + tid + pi * 512];
            #pragma unroll
            for (int k = 0; k < 4; ++k) accq[pi][k] += xv * wv[k];
        }
    }
    #pragma unroll
    for (int pi = 0; pi < 2; ++pi) {
        int p = tid + pi * 512;
        *(float4*)&qs[p * 4] = make_float4(accq[pi][0], accq[pi][1], accq[pi][2], accq[pi][3]);
        #pragma unroll
        for (int k = 0; k < 4; ++k)
            q[(size_t)(bg * ODIM + o0 + k) * PQ + p] = accq[pi][k];
    }
    __syncthreads();

    {
        int cl = tid & 3, j = tid >> 2;   // 512 units = 128 j x 4 c
        int c = o0 + cl;
        int xo = j & 7, yo = (j >> 3) & 7, zo = j >> 6;
        const float* wd = dww + c * 64;
        float acc = dwb[c];
        #pragma unroll
        for (int kz = 0; kz < 4; ++kz) {
            int z = 2 * zo - 1 + kz;
            if (z < 0 || z >= FF) continue;
            #pragma unroll
            for (int ky = 0; ky < 4; ++ky) {
                int y = 2 * yo - 1 + ky;
                if (y < 0 || y >= HH) continue;
                #pragma unroll
                for (int kx = 0; kx < 4; ++kx) {
                    int xx = 2 * xo - 1 + kx;
                    if (xx < 0 || xx >= WW) continue;
                    acc += qs[((z * HH + y) * WW + xx) * 4 + cl] * wd[(kz * 4 + ky) * 4 + kx];
                }
            }
        }
        act[((size_t)bg * PJ + j) * ODIM + c] =
            0.5f * acc * (1.0f + erff(acc * 0.70710678118654752f));
    }
}

// ------- fused offsets -> grid -> trilinear sample -> k/v proj; 2 j's per block
__global__ __launch_bounds__(256) void k_kvf(
    const float* __restrict__ act, const float* __restrict__ pw,
    const float* __restrict__ x, const float* __restrict__ wk,
    const float* __restrict__ wv, float* __restrict__ gkv,
    float* __restrict__ kk2, float* __restrict__ vvT2) {
    __shared__ float red2[2][6];
    __shared__ float crd[2][3];
    __shared__ float kvs[2][64];
    int blk = blockIdx.x;            // bg*64 + jt
    int jt = blk & 63, bg = blk >> 6;
    int b = bg >> 2, g = bg & 3;
    int tid = threadIdx.x;
    int half = tid >> 7;
    int t = tid & 127;
    int j = jt * 2 + half;
    int wv_ = t >> 6;

    float val = act[((size_t)bg * PJ + j) * ODIM + t];
    float s0 = val * pw[t];
    float s1 = val * pw[ODIM + t];
    float s2 = val * pw[2 * ODIM + t];
    #pragma unroll
    for (int off = 32; off; off >>= 1) {
        s0 += __shfl_xor(s0, off);
        s1 += __shfl_xor(s1, off);
        s2 += __shfl_xor(s2, off);
    }
    if ((t & 63) == 0) {
        red2[half][wv_ * 3] = s0; red2[half][wv_ * 3 + 1] = s1; red2[half][wv_ * 3 + 2] = s2;
    }
    __syncthreads();
    if (t == 0) {
        s0 = red2[half][0] + red2[half][3];
        s1 = red2[half][1] + red2[half][4];
        s2 = red2[half][2] + red2[half][5];
        float xo = (float)(j & 7), yo = (float)((j >> 3) & 7), zo = (float)(j >> 6);
        float vf = zo + 2.f * tanhf(s0);
        float vh = yo + 2.f * tanhf(s1);
        float vw = xo + 2.f * tanhf(s2);
        float c0 = 2.f * vf - 1.f;
        float c1 = 2.f * vh / 7.f - 1.f;
        float c2 = 2.f * vw / 7.f - 1.f;
        crd[half][0] = c0; crd[half][1] = c1; crd[half][2] = c2;
        gkv[(bg * PJ + j) * 3 + 0] = c0;
        gkv[(bg * PJ + j) * 3 + 1] = c1;
        gkv[(bg * PJ + j) * 3 + 2] = c2;
    }
    __syncthreads();

    // BUG-COMPATIBLE: crd[0] (f-coord) -> x/W axis, crd[1] -> y/H, crd[2] (w) -> z/D.
    if (t < 64) {
        float ix = ((crd[half][0] + 1.f) * WW - 1.f) * 0.5f;
        float iy = ((crd[half][1] + 1.f) * HH - 1.f) * 0.5f;
        float iz = ((crd[half][2] + 1.f) * FF - 1.f) * 0.5f;
        float x0f = floorf(ix), y0f = floorf(iy), z0f = floorf(iz);
        float tx = ix - x0f, ty = iy - y0f, tz = iz - z0f;
        int x0 = (int)x0f, y0 = (int)y0f, z0 = (int)z0f;
        const float* vol = x + (size_t)(b * DIMC + g * CPG + t) * PQ;
        float acc = 0.f;
        #pragma unroll
        for (int dz = 0; dz < 2; ++dz) {
            int zc = z0 + dz;
            if (zc < 0 || zc >= FF) continue;
            float wz = dz ? tz : 1.f - tz;
            #pragma unroll
            for (int dy = 0; dy < 2; ++dy) {
                int yc = y0 + dy;
                if (yc < 0 || yc >= HH) continue;
                float wy = dy ? ty : 1.f - ty;
                #pragma unroll
                for (int dx = 0; dx < 2; ++dx) {
                    int xc = x0 + dx;
                    if (xc < 0 || xc >= WW) continue;
                    float wgt = wz * wy * (dx ? tx : 1.f - tx);
                    acc += vol[(zc * HH + yc) * WW + xc] * wgt;
                }
            }
        }
        kvs[half][t] = acc;
    }
    __syncthreads();

    const float* wkp = wk + (size_t)(g * ODIM + t) * CPG;
    const float* wvp = wv + (size_t)(g * ODIM + t) * CPG;
    float ak = 0.f, av = 0.f;
    #pragma unroll
    for (int i = 0; i < 64; i += 4) {
        float4 kv4 = *(const float4*)&kvs[half][i];
        float4 wk4 = *(const float4*)&wkp[i];
        float4 wv4 = *(const float4*)&wvp[i];
        ak += kv4.x * wk4.x + kv4.y * wk4.y + kv4.z * wk4.z + kv4.w * wk4.w;
        av += kv4.x * wv4.x + kv4.y * wv4.y + kv4.z * wv4.z + kv4.w * wv4.w;
    }
    kk2[((size_t)(bg * 64 + (t & 63)) * PJ + j) * 2 + (t >> 6)] = ak;
    vvT2[((size_t)(bg * 64 + (j >> 1)) * ODIM + t) * 2 + (j & 1)] = av;
}

// ---- fused CPB (f16 MFMA, bias to LDS) + QK^T + softmax + attn*V; 16 queries/block
// R14 structure; layer-0 h0-build + layer-1 MFMA in f16 via native _Float16 vectors
__global__ __launch_bounds__(256) void k_cpa(
    const float* __restrict__ q, const float* __restrict__ kk2,
    const float* __restrict__ vvT2, const float* __restrict__ gkv,
    const float* __restrict__ w0, const float* __restrict__ b0,
    const float* __restrict__ w1, const float* __restrict__ b1,
    const float* __restrict__ w2, const float* __restrict__ b2,
    float* __restrict__ outh) {
    __shared__ __align__(16) float tbuf[4 * 2176];   // 34816 B; phase-B alias below
    __shared__ __align__(16) float biasL[16 * 256];  // [il][j]*2 heads interleaved: 16 KB
    __shared__ float redA[64];
    float* attL = tbuf;              // 16*256 floats
    float* qsL  = tbuf + 4096;       // 16*128 floats

    int blk = blockIdx.x;            // bg*64 + it
    int it = blk & 63, bg = blk >> 6;
    int b = bg >> 2, g = bg & 3;
    int tid = threadIdx.x;
    int w = tid >> 6, lane = tid & 63, col = lane & 15, quad = lane >> 4;

    // ---------------- phase A: CPB (barrier-free per wave) ----------------
    // W1 B-fragments in f16
    uint4 bfr[2][4];
    #pragma unroll
    for (int kc = 0; kc < 2; ++kc)
        #pragma unroll
        for (int nt = 0; nt < 4; ++nt) {
            int n = nt * 16 + col;
            int kbase = kc * 32 + quad * 8;
            unsigned int pk[4];
            #pragma unroll
            for (int p = 0; p < 4; ++p) {
                f16x2 hv = {(_Float16)w1[(kbase + 2 * p) * 64 + n],
                            (_Float16)w1[(kbase + 2 * p + 1) * 64 + n]};
                pk[p] = *(unsigned int*)&hv;
            }
            bfr[kc][nt] = make_uint4(pk[0], pk[1], pk[2], pk[3]);
        }

    // f16 w0/b0 slices for this lane's dims (query-invariant, hoisted)
    f16x2 w0a[2][4], w0b[2][4], w0c[2][4], b0h[2][4];
    #pragma unroll
    for (int kc = 0; kc < 2; ++kc) {
        int d0 = kc * 32 + quad * 8;
        #pragma unroll
        for (int pr = 0; pr < 4; ++pr) {
            w0a[kc][pr] = (f16x2){(_Float16)w0[d0 + 2 * pr], (_Float16)w0[d0 + 2 * pr + 1]};
            w0b[kc][pr] = (f16x2){(_Float16)w0[64 + d0 + 2 * pr], (_Float16)w0[64 + d0 + 2 * pr + 1]};
            w0c[kc][pr] = (f16x2){(_Float16)w0[128 + d0 + 2 * pr], (_Float16)w0[128 + d0 + 2 * pr + 1]};
            b0h[kc][pr] = (f16x2){(_Float16)b0[d0 + 2 * pr], (_Float16)b0[d0 + 2 * pr + 1]};
        }
    }
    f16x2 zero2 = {(_Float16)0.f, (_Float16)0.f};

    float g0r[8], g1r[8], g2r[8];
    #pragma unroll
    for (int mtg = 0; mtg < 8; ++mtg) {
        int jr = mtg * 16 + col;
        g0r[mtg] = gkv[(bg * PJ + jr) * 3 + 0];
        g1r[mtg] = gkv[(bg * PJ + jr) * 3 + 1];
        g2r[mtg] = gkv[(bg * PJ + jr) * 3 + 2];
    }
    float b1v[4]; f32x2 w2v[4];
    #pragma unroll
    for (int nt = 0; nt < 4; ++nt) {
        int jj = nt * 16 + col;
        b1v[nt] = b1[jj];
        w2v[nt] = *(const f32x2*)&w2[jj * 2];
    }
    f32x2 bias_b2 = *(const f32x2*)b2;
    f32x2* mytb = (f32x2*)&tbuf[w * 2176];

    #pragma unroll 1
    for (int ii = 0; ii < 4; ++ii) {
        int il = w * 4 + ii;
        int i = it * 16 + il;
        int wq_ = i & 15, hq = (i >> 4) & 15, fq = i >> 8;
        float cq0 = 2.f * fq / 3.f - 1.f;
        float cq1 = 2.f * hq / 15.f - 1.f;
        float cq2 = 2.f * wq_ / 15.f - 1.f;

        #pragma unroll 1
        for (int mh = 0; mh < 2; ++mh) {
            f16x2 t0h[4], t1h[4], t2h[4];
            #pragma unroll
            for (int mt = 0; mt < 4; ++mt) {
                int mtg = mh * 4 + mt;
                float p0 = cq0 - g0r[mtg];
                float p1 = cq1 - g1r[mtg];
                float p2 = cq2 - g2r[mtg];
                float t0 = copysignf(__logf(1.f + fabsf(p0)), p0);
                float t1 = copysignf(__logf(1.f + fabsf(p1)), p1);
                float t2 = copysignf(__logf(1.f + fabsf(p2)), p2);
                _Float16 h0 = (_Float16)t0, h1 = (_Float16)t1, h2 = (_Float16)t2;
                t0h[mt] = (f16x2){h0, h0};
                t1h[mt] = (f16x2){h1, h1};
                t2h[mt] = (f16x2){h2, h2};
            }
            f32x4 acc[4][4] = {};
            #pragma unroll
            for (int kc = 0; kc < 2; ++kc) {
                #pragma unroll
                for (int mt = 0; mt < 4; ++mt) {
                    unsigned int pk[4];
                    #pragma unroll
                    for (int pr = 0; pr < 4; ++pr) {
                        f16x2 z = b0h[kc][pr];
                        z += t0h[mt] * w0a[kc][pr];
                        z += t1h[mt] * w0b[kc][pr];
                        z += t2h[mt] * w0c[kc][pr];
                        z = __builtin_elementwise_max(z, zero2);
                        pk[pr] = *(unsigned int*)&z;
                    }
                    uint4 afu = make_uint4(pk[0], pk[1], pk[2], pk[3]);
                    f16x8 af = *(f16x8*)&afu;
                    #pragma unroll
                    for (int nt = 0; nt < 4; ++nt)
                        acc[mt][nt] = __builtin_amdgcn_mfma_f32_16x16x32_f16(
                            af, *(f16x8*)&bfr[kc][nt], acc[mt][nt], 0, 0, 0);
                }
            }
            #pragma unroll
            for (int mt = 0; mt < 4; ++mt)
                #pragma unroll
                for (int reg = 0; reg < 4; ++reg) {
                    f32x2 pp = {0.f, 0.f};
                    #pragma unroll
                    for (int nt = 0; nt < 4; ++nt) {
                        float hv = fmaxf(acc[mt][nt][reg] + b1v[nt], 0.f);
                        pp += hv * w2v[nt];
                    }
                    mytb[(mt * 16 + quad * 4 + reg) * 17 + col] = pp;
                }
            f32x2 s = bias_b2;
            {
                const f32x2* pr2 = mytb + lane * 17;
                #pragma unroll
                for (int c = 0; c < 16; ++c) s += pr2[c];
            }
            int jl = mh * 64 + lane;
            *(f32x2*)&biasL[(il * 128 + jl) * 2] = s;
        }
    }
    __syncthreads();   // phase A complete; tbuf now reusable as attL/qsL

    // ---------------- phase B: attention for 16 queries ----------------
    int half = tid >> 7;             // i-half (8 queries each)
    int j = tid & 127;               // also channel index in AV

    {
        const float* qp = q + (size_t)(bg * ODIM + j) * PQ + it * 16 + half * 8;
        float4 qa = *(const float4*)qp;
        float4 qb = *(const float4*)(qp + 4);
        int e = j >> 6, d = j & 63;
        qsL[(half * 8 + 0) * 128 + d * 2 + e] = qa.x * 0.125f;
        qsL[(half * 8 + 1) * 128 + d * 2 + e] = qa.y * 0.125f;
        qsL[(half * 8 + 2) * 128 + d * 2 + e] = qa.z * 0.125f;
        qsL[(half * 8 + 3) * 128 + d * 2 + e] = qa.w * 0.125f;
        qsL[(half * 8 + 4) * 128 + d * 2 + e] = qb.x * 0.125f;
        qsL[(half * 8 + 5) * 128 + d * 2 + e] = qb.y * 0.125f;
        qsL[(half * 8 + 6) * 128 + d * 2 + e] = qb.z * 0.125f;
        qsL[(half * 8 + 7) * 128 + d * 2 + e] = qb.w * 0.125f;
    }
    __syncthreads();

    f32x2 sc[8];
    #pragma unroll
    for (int k = 0; k < 8; ++k)
        sc[k] = *(const f32x2*)&biasL[((half * 8 + k) * 128 + j) * 2];

    {
        const f32x2* kp = (const f32x2*)kk2 + (size_t)(bg * 64) * PJ + j;
        const f32x2* qs2 = (const f32x2*)qsL;
        #pragma unroll 4
        for (int d = 0; d < 64; ++d) {
            f32x2 kv2 = kp[(size_t)d * PJ];
            #pragma unroll
            for (int k = 0; k < 8; ++k)
                sc[k] += qs2[(half * 8 + k) * 64 + d] * kv2;
        }
    }
    #pragma unroll
    for (int k = 0; k < 8; ++k) {
        int il = half * 8 + k;
        attL[il * 256 + j] = sc[k].x;
        attL[il * 256 + 128 + j] = sc[k].y;
    }
    __syncthreads();

    // softmax: 32 rows (il, head); wave w handles rows w*8..w*8+7
    #pragma unroll
    for (int rr = 0; rr < 8; ++rr) {
        int r = w * 8 + rr;
        int il = r >> 1, hd = r & 1;
        float a0 = attL[il * 256 + hd * 128 + lane];
        float a1 = attL[il * 256 + hd * 128 + 64 + lane];
        float mx = fmaxf(a0, a1);
        #pragma unroll
        for (int off = 32; off; off >>= 1) mx = fmaxf(mx, __shfl_xor(mx, off));
        float ex = __expf(a0 - mx) + __expf(a1 - mx);
        #pragma unroll
        for (int off = 32; off; off >>= 1) ex += __shfl_xor(ex, off);
        if (lane == 0) { redA[r * 2] = mx; redA[r * 2 + 1] = ex; }
    }
    __syncthreads();
    #pragma unroll
    for (int k = 0; k < 8; ++k) {
        int il = half * 8 + k;
        float p0n = __expf(sc[k].x - redA[(il * 2 + 0) * 2]) * (1.f / redA[(il * 2 + 0) * 2 + 1]);
        float p1n = __expf(sc[k].y - redA[(il * 2 + 1) * 2]) * (1.f / redA[(il * 2 + 1) * 2 + 1]);
        attL[il * 256 + j] = p0n;
        attL[il * 256 + 128 + j] = p1n;
    }
    __syncthreads();

    // attn * V: thread (half, ch=j) computes 8 i's of channel j
    {
        const f32x2* vp = (const f32x2*)vvT2 + (size_t)(bg * 64) * ODIM + j;
        int e = j >> 6;
        f32x2 oacc[8] = {};
        #pragma unroll 4
        for (int jp = 0; jp < 64; ++jp) {
            f32x2 vv2 = vp[(size_t)jp * ODIM];
            #pragma unroll
            for (int k = 0; k < 8; ++k) {
                f32x2 ap2 = *(const f32x2*)&attL[(half * 8 + k) * 256 + e * 128 + jp * 2];
                oacc[k] += ap2 * vv2;
            }
        }
        #pragma unroll
        for (int k = 0; k < 8; ++k)
            outh[((size_t)b * PQ + it * 16 + half * 8 + k) * INNERC + g * 128 + j] =
                oacc[k].x + oacc[k].y;
    }
}

// ---- final projection: LDS-tiled fp32 GEMM. M=2048 (b*p), N=256 (o), K=512.
__global__ __launch_bounds__(256) void k_out(
    const float* __restrict__ outh, const float* __restrict__ wo,
    const float* __restrict__ bo, float* __restrict__ out) {
    __shared__ float At[32][68];
    __shared__ float Bt[32][36];
    int blk = blockIdx.x;            // 0..255
    int nt = blk & 7, mt = blk >> 3;
    int m0 = mt * 64, o0 = nt * 32;
    int tid = threadIdx.x;
    int tm = tid >> 4, tn = tid & 15;
    int mloc = tm * 4, nloc = tn * 2;

    int ra = tid >> 2, ca = (tid & 3) * 8;
    int rb = tid >> 3, cb = (tid & 7) * 4;

    float4 pa0, pa1, pb;
    {
        const float* Ap = outh + (size_t)(m0 + ra) * INNERC + ca;
        pa0 = *(const float4*)Ap;
        pa1 = *(const float4*)(Ap + 4);
        pb = *(const float4*)(wo + (size_t)(o0 + rb) * INNERC + cb);
    }

    float acc[4][2] = {};
    for (int ch = 0; ch < 16; ++ch) {
        #pragma unroll
        for (int k = 0; k < 4; ++k) {
            At[ca + k][ra] = ((const float*)&pa0)[k];
            At[ca + 4 + k][ra] = ((const float*)&pa1)[k];
            Bt[cb + k][rb] = ((const float*)&pb)[k];
        }
        __syncthreads();
        if (ch < 15) {
            int c0 = (ch + 1) * 32;
            const float* Ap = outh + (size_t)(m0 + ra) * INNERC + c0 + ca;
            pa0 = *(const float4*)Ap;
            pa1 = *(const float4*)(Ap + 4);
            pb = *(const float4*)(wo + (size_t)(o0 + rb) * INNERC + c0 + cb);
        }
        #pragma unroll
        for (int kk = 0; kk < 32; ++kk) {
            float4 a4 = *(const float4*)&At[kk][mloc];
            float2 b2 = *(const float2*)&Bt[kk][nloc];
            #pragma unroll
            for (int i = 0; i < 4; ++i) {
                float av = ((const float*)&a4)[i];
                acc[i][0] += av * b2.x;
                acc[i][1] += av * b2.y;
            }
        }
        __syncthreads();
    }

    #pragma unroll
    for (int jn = 0; jn < 2; ++jn) {
        int o = o0 + nloc + jn;
        float bv = bo[o];
        #pragma unroll
        for (int i = 0; i < 4; ++i) {
            int m = m0 + mloc + i;
            int b = m >> 10, p = m & 1023;
            out[((size_t)(b * DIMC + o)) * PQ + p] = acc[i][jn] + bv;
        }
    }
}

extern "C" void kernel_launch(void* const* d_in, const int* in_sizes, int n_in,
                              void* d_out, int out_size, void* d_ws, size_t ws_size,
                              hipStream_t stream) {
    const float* x   = (const float*)d_in[0];
    const float* wq  = (const float*)d_in[1];
    const float* wk  = (const float*)d_in[2];
    const float* wv  = (const float*)d_in[3];
    const float* dww = (const float*)d_in[4];
    const float* dwb = (const float*)d_in[5];
    const float* pw  = (const float*)d_in[6];
    const float* w0  = (const float*)d_in[7];
    const float* b0  = (const float*)d_in[8];
    const float* w1  = (const float*)d_in[9];
    const float* b1  = (const float*)d_in[10];
    const float* w2  = (const float*)d_in[11];
    const float* b2  = (const float*)d_in[12];
    const float* wo  = (const float*)d_in[13];
    const float* bo  = (const float*)d_in[14];
    float* out = (float*)d_out;

    float* ws_f  = (float*)d_ws;
    float* q     = ws_f;                  // 1048576
    float* act   = q + 1048576;           // 131072
    float* gkv   = act + 131072;          // 3072
    float* kk2   = gkv + 3072;            // 131072
    float* vvT2  = kk2 + 131072;          // 131072
    float* outh  = vvT2 + 131072;         // 1048576

    k_qdw<<<256, 512, 0, stream>>>(x, wq, dww, dwb, q, act);
    k_kvf<<<512, 256, 0, stream>>>(act, pw, x, wk, wv, gkv, kk2, vvT2);
    k_cpa<<<512, 256, 0, stream>>>(q, kk2, vvT2, gkv, w0, b0, w1, b1, w2, b2, outh);
    k_out<<<256, 256, 0, stream>>>(outh, wo, bo, out);
}